// Round 4
// baseline (245.825 us; speedup 1.0000x reference)
//
#include <hip/hip_runtime.h>

#define N 8192
#define D 128
#define CHUNK 512
#define NCHUNK 16
#define TILE_IT 4
// sqrt(10 * log2(e)): dot of two scaled rows = log2(e^{cos/T}) -> e = exp2(acc)
#define PREP_SCALE 3.7982889979f

typedef unsigned short u16;
typedef __attribute__((ext_vector_type(8))) __bf16 bf16x8;
typedef __attribute__((ext_vector_type(4))) float f32x4;

__device__ __forceinline__ float fast_exp2(float x) {
#if __has_builtin(__builtin_amdgcn_exp2f)
  return __builtin_amdgcn_exp2f(x);  // single v_exp_f32; |arg| <= 14.5 here
#else
  return exp2f(x);
#endif
}

__device__ __forceinline__ u16 f2bf(float x) {
  unsigned u = __float_as_uint(x);
  u += 0x7fff + ((u >> 16) & 1);  // RNE
  return (u16)(u >> 16);
}
__device__ __forceinline__ float bf2f(u16 h) {
  return __uint_as_float(((unsigned)h) << 16);
}

// ---- kernel 1: normalize+scale rows, ZERO bg rows, split hi/lo; zero accum -
__global__ __launch_bounds__(256) void cpe_prep(const float* __restrict__ feat,
                                                const int* __restrict__ labels,
                                                u16* __restrict__ fhi,
                                                u16* __restrict__ flo,
                                                float* __restrict__ accum) {
  if (blockIdx.x == 0 && threadIdx.x < 4) accum[threadIdx.x] = 0.0f;
  const int w = threadIdx.x >> 6, l = threadIdx.x & 63, q = l >> 4, m = l & 15;
  const int row = (int)blockIdx.x * 16 + w * 4 + q;  // 16 rows/block
  const int lab = labels[row];
  const float4 x0 = *(const float4*)&feat[row * D + m * 8];
  const float4 x1 = *(const float4*)&feat[row * D + m * 8 + 4];
  float s = x0.x * x0.x + x0.y * x0.y + x0.z * x0.z + x0.w * x0.w +
            x1.x * x1.x + x1.y * x1.y + x1.z * x1.z + x1.w * x1.w;
#pragma unroll
  for (int sh = 1; sh < 16; sh <<= 1) s += __shfl_xor(s, sh);
  float inv = PREP_SCALE / fmaxf(sqrtf(s), 1e-12f);
  if (lab < 0) inv = 0.0f;  // bg rows -> sim=0 -> e=1, subtracted exactly later
  const float a[8] = {x0.x * inv, x0.y * inv, x0.z * inv, x0.w * inv,
                      x1.x * inv, x1.y * inv, x1.z * inv, x1.w * inv};
  u16 h[8], lo[8];
#pragma unroll
  for (int k = 0; k < 8; ++k) {
    h[k] = f2bf(a[k]);
    lo[k] = f2bf(a[k] - bf2f(h[k]));
  }
  *(ushort4*)&fhi[row * D + m * 8] = make_ushort4(h[0], h[1], h[2], h[3]);
  *(ushort4*)&fhi[row * D + m * 8 + 4] = make_ushort4(h[4], h[5], h[6], h[7]);
  *(ushort4*)&flo[row * D + m * 8] = make_ushort4(lo[0], lo[1], lo[2], lo[3]);
  *(ushort4*)&flo[row * D + m * 8 + 4] = make_ushort4(lo[4], lo[5], lo[6], lo[7]);
}

// ---- kernel 2: sim = (Ahi+Alo)·Bhi, unmasked e-sums, exact self capture ----
// Grid (32, 16): block = 256 rows x 512-col chunk; wave owns 64 rows.
__global__ __launch_bounds__(256, 2) void cpe_main(
    const u16* __restrict__ fhi, const u16* __restrict__ flo,
    const int* __restrict__ labels, float2* __restrict__ partials,
    float* __restrict__ eself) {
  __shared__ __align__(16) u16 Bh[128 * 128];  // 32 KB, XOR-swizzled chunks
  const int rt = blockIdx.x, cc = blockIdx.y;
  const int tid = threadIdx.x;
  const int w = tid >> 6, l = tid & 63, q = l >> 4, m = l & 15;
  const int r0w = rt * 256 + w * 64;
  const int cbase0 = cc * CHUNK;

  bf16x8 Ah[4][4], Al[4][4];  // wave's 64 rows, hi+lo, straight from L2
  int labi[4][4];
#pragma unroll
  for (int tr = 0; tr < 4; ++tr) {
    const int row = r0w + tr * 16 + m;
#pragma unroll
    for (int ks = 0; ks < 4; ++ks) {
      Ah[tr][ks] = *(const bf16x8*)&fhi[row * D + ks * 32 + q * 8];
      Al[tr][ks] = *(const bf16x8*)&flo[row * D + ks * 32 + q * 8];
    }
#pragma unroll
    for (int v = 0; v < 4; ++v) labi[tr][v] = labels[r0w + tr * 16 + q * 4 + v];
  }

  float ps[4][4], as_[4][4], bgc = 0.f;
#pragma unroll
  for (int tr = 0; tr < 4; ++tr)
#pragma unroll
    for (int v = 0; v < 4; ++v) { ps[tr][v] = 0.f; as_[tr][v] = 0.f; }

  for (int it = 0; it < TILE_IT; ++it) {
    const int cbase = cbase0 + it * 128;
    __syncthreads();  // prior tile's LDS reads done
#pragma unroll
    for (int n = 0; n < 8; ++n) {  // stage Bhi via 16B global->LDS DMA
      const int r = w * 32 + n * 4 + q;
      const int c = m ^ (r & 15);  // XOR swizzle folded into global addr
      __builtin_amdgcn_global_load_lds(
          (const __attribute__((address_space(1))) unsigned*)
              &fhi[(size_t)(cbase + r) * D + c * 8],
          (__attribute__((address_space(3))) unsigned*)
              &Bh[(w * 512 + n * 64) * 8],
          16, 0, 0);
    }
    __syncthreads();  // drains vmcnt

    for (int ct = 0; ct < 8; ++ct) {
      const int jj = ct * 16 + m;
      const int jbase = cbase + ct * 16;
      const int labj = labels[jbase + m];  // hoisted: hides vmcnt behind MFMA
      f32x4 acc[4];
#pragma unroll
      for (int tr = 0; tr < 4; ++tr) acc[tr] = (f32x4){0.f, 0.f, 0.f, 0.f};
#pragma unroll
      for (int ks = 0; ks < 4; ++ks) {
        const bf16x8 bh = *(const bf16x8*)&Bh[jj * 128 + ((ks * 4 + q) ^ m) * 8];
#pragma unroll
        for (int tr = 0; tr < 4; ++tr)
          acc[tr] = __builtin_amdgcn_mfma_f32_16x16x32_bf16(Ah[tr][ks], bh, acc[tr], 0, 0, 0);
#pragma unroll
        for (int tr = 0; tr < 4; ++tr)
          acc[tr] = __builtin_amdgcn_mfma_f32_16x16x32_bf16(Al[tr][ks], bh, acc[tr], 0, 0, 0);
      }
      bgc += (labj < 0) ? 1.0f : 0.0f;  // once per ct; per-lane bg col count
#pragma unroll
      for (int tr = 0; tr < 4; ++tr) {
        if (jbase == r0w + tr * 16) {  // wave-uniform: diagonal tile
#pragma unroll
          for (int v = 0; v < 4; ++v) {
            const float e = fast_exp2(acc[tr][v]);
            if (m == q * 4 + v) eself[jbase + m] = e;  // exact self term
            as_[tr][v] += e;
            ps[tr][v] += (labj == labi[tr][v]) ? e : 0.f;
          }
        } else {
#pragma unroll
          for (int v = 0; v < 4; ++v) {  // 5-op epilogue: exp,add,cmp,sel,add
            const float e = fast_exp2(acc[tr][v]);
            as_[tr][v] += e;
            ps[tr][v] += (labj == labi[tr][v]) ? e : 0.f;
          }
        }
      }
    }
  }

  // reduce over the 16 m-lanes (disjoint columns of each row)
  float vbg = bgc;
#pragma unroll
  for (int s = 1; s < 16; s <<= 1) vbg += __shfl_xor(vbg, s);
#pragma unroll
  for (int tr = 0; tr < 4; ++tr)
#pragma unroll
    for (int v = 0; v < 4; ++v) {
      float vp = ps[tr][v], va = as_[tr][v];
#pragma unroll
      for (int s = 1; s < 16; s <<= 1) {
        vp += __shfl_xor(vp, s);
        va += __shfl_xor(va, s);
      }
      if (m == 0)  // bg columns each contributed exactly e=1: subtract
        partials[(size_t)cc * N + r0w + tr * 16 + q * 4 + v] =
            make_float2(vp, va - vbg);
    }
}

// ---- kernel 3: combine chunks, exact corrections, loss, mean (finalizes) ---
__global__ __launch_bounds__(256) void cpe_rows(const float2* __restrict__ partials,
                                                const int* __restrict__ labels,
                                                const float* __restrict__ eself,
                                                float* __restrict__ accum,
                                                float* __restrict__ out) {
  const int r = blockIdx.x * 256 + threadIdx.x;
  float ps = 0.f, as_ = 0.f;
#pragma unroll
  for (int c = 0; c < NCHUNK; ++c) {
    const float2 p = partials[(size_t)c * N + r];
    ps += p.x;
    as_ += p.y;
  }
  const float es = eself[r];
  const int lab = labels[r];
  ps -= es;   // self always label-matches; exact cancellation if no positives
  as_ -= es;  // bg columns already removed per-chunk
  const bool valid = (lab >= 0) && (ps > 0.f);
  // |sim|<=10 => max-clamp inactive; all_sum*e^-M in [1,8191] => its clips
  // inactive; pos-clip binding forces loss=10 either way => clip-free form.
  float loss = 10.0f;
  if (ps > 0.f && as_ > 0.f) loss = fminf(logf(as_ / ps), 10.0f);
  float v0 = valid ? loss : 0.f;
  float v1 = valid ? 1.f : 0.f;
  float v2 = (lab >= 0) ? 1.f : 0.f;
#pragma unroll
  for (int s = 1; s < 64; s <<= 1) {
    v0 += __shfl_xor(v0, s);
    v1 += __shfl_xor(v1, s);
    v2 += __shfl_xor(v2, s);
  }
  __shared__ float red[3][4];
  const int w = threadIdx.x >> 6, l = threadIdx.x & 63;
  if (l == 0) { red[0][w] = v0; red[1][w] = v1; red[2][w] = v2; }
  __syncthreads();
  if (threadIdx.x == 0) {
    atomicAdd(&accum[0], red[0][0] + red[0][1] + red[0][2] + red[0][3]);
    atomicAdd(&accum[1], red[1][0] + red[1][1] + red[1][2] + red[1][3]);
    atomicAdd(&accum[2], red[2][0] + red[2][1] + red[2][2] + red[2][3]);
    __threadfence();
    const unsigned old = atomicAdd((unsigned*)&accum[3], 1u);
    if (old == gridDim.x - 1) {  // last block finalizes
      const float ls = atomicAdd(&accum[0], 0.0f);
      const float nv = atomicAdd(&accum[1], 0.0f);
      const float nf = atomicAdd(&accum[2], 0.0f);
      out[0] = (nf >= 2.0f && nv > 0.f) ? ls / fmaxf(nv, 1.f) : 0.0f;
    }
  }
}

extern "C" void kernel_launch(void* const* d_in, const int* in_sizes, int n_in,
                              void* d_out, int out_size, void* d_ws, size_t ws_size,
                              hipStream_t stream) {
  const float* feat = (const float*)d_in[0];
  const int* labels = (const int*)d_in[1];
  float* out = (float*)d_out;
  char* ws = (char*)d_ws;
  u16* fhi = (u16*)ws;                          // 2 MB
  u16* flo = (u16*)(ws + 2097152);              // 2 MB
  float2* partials = (float2*)(ws + 4194304);   // 16*8192*8 = 1 MB
  float* eself = (float*)(ws + 5242880);        // 32 KB
  float* accum = (float*)(ws + 5275648);        // loss-sum, n_valid, n_fg, ctr

  cpe_prep<<<N / 16, 256, 0, stream>>>(feat, labels, fhi, flo, accum);
  cpe_main<<<dim3(N / 256, NCHUNK), 256, 0, stream>>>(fhi, flo, labels, partials, eself);
  cpe_rows<<<N / 256, 256, 0, stream>>>(partials, labels, eself, accum, out);
}

// Round 5
// 149.987 us; speedup vs baseline: 1.6390x; 1.6390x over previous
//
#include <hip/hip_runtime.h>

#define N 8192
#define D 128
#define CHUNK 512
#define NCHUNK 16
#define TILE_IT 4
// sqrt(10 * log2(e)): dot of two scaled rows = log2(e^{cos/T}) -> e = exp2(acc)
#define PREP_SCALE 3.7982889979f

typedef unsigned short u16;
typedef __attribute__((ext_vector_type(8))) __bf16 bf16x8;
typedef __attribute__((ext_vector_type(4))) float f32x4;

__device__ __forceinline__ float fast_exp2(float x) {
#if __has_builtin(__builtin_amdgcn_exp2f)
  return __builtin_amdgcn_exp2f(x);  // single v_exp_f32; |arg| <= 14.5 here
#else
  return exp2f(x);
#endif
}

__device__ __forceinline__ u16 f2bf(float x) {
  unsigned u = __float_as_uint(x);
  u += 0x7fff + ((u >> 16) & 1);  // RNE
  return (u16)(u >> 16);
}
__device__ __forceinline__ float bf2f(u16 h) {
  return __uint_as_float(((unsigned)h) << 16);
}

// ---- kernel 1: normalize+scale rows, ZERO bg rows, split hi/lo; zero accum -
__global__ __launch_bounds__(256) void cpe_prep(const float* __restrict__ feat,
                                                const int* __restrict__ labels,
                                                u16* __restrict__ fhi,
                                                u16* __restrict__ flo,
                                                float* __restrict__ accum) {
  if (blockIdx.x == 0 && threadIdx.x < 4) accum[threadIdx.x] = 0.0f;
  const int w = threadIdx.x >> 6, l = threadIdx.x & 63, q = l >> 4, m = l & 15;
  const int row = (int)blockIdx.x * 16 + w * 4 + q;  // 16 rows/block
  const int lab = labels[row];
  const float4 x0 = *(const float4*)&feat[row * D + m * 8];
  const float4 x1 = *(const float4*)&feat[row * D + m * 8 + 4];
  float s = x0.x * x0.x + x0.y * x0.y + x0.z * x0.z + x0.w * x0.w +
            x1.x * x1.x + x1.y * x1.y + x1.z * x1.z + x1.w * x1.w;
#pragma unroll
  for (int sh = 1; sh < 16; sh <<= 1) s += __shfl_xor(s, sh);
  float inv = PREP_SCALE / fmaxf(sqrtf(s), 1e-12f);
  if (lab < 0) inv = 0.0f;  // bg rows -> sim=0 -> e=1, subtracted exactly later
  const float a[8] = {x0.x * inv, x0.y * inv, x0.z * inv, x0.w * inv,
                      x1.x * inv, x1.y * inv, x1.z * inv, x1.w * inv};
  u16 h[8], lo[8];
#pragma unroll
  for (int k = 0; k < 8; ++k) {
    h[k] = f2bf(a[k]);
    lo[k] = f2bf(a[k] - bf2f(h[k]));
  }
  *(ushort4*)&fhi[row * D + m * 8] = make_ushort4(h[0], h[1], h[2], h[3]);
  *(ushort4*)&fhi[row * D + m * 8 + 4] = make_ushort4(h[4], h[5], h[6], h[7]);
  *(ushort4*)&flo[row * D + m * 8] = make_ushort4(lo[0], lo[1], lo[2], lo[3]);
  *(ushort4*)&flo[row * D + m * 8 + 4] = make_ushort4(lo[4], lo[5], lo[6], lo[7]);
}

// ---- kernel 2: sim = Ah·(Bh+Bl); Ah regs (64 VGPR), Bh+Bl in LDS (no spill!)
// Grid (32, 16): block = 256 rows x 512-col chunk; wave owns 64 rows.
__global__ __launch_bounds__(256, 2) void cpe_main(
    const u16* __restrict__ fhi, const u16* __restrict__ flo,
    const int* __restrict__ labels, float2* __restrict__ partials,
    float* __restrict__ eself) {
  __shared__ __align__(16) u16 Bh[128 * 128];  // 32 KB, XOR-swizzled chunks
  __shared__ __align__(16) u16 Bl[128 * 128];  // 32 KB
  __shared__ int Lab[CHUNK];                   // 2 KB
  const int rt = blockIdx.x, cc = blockIdx.y;
  const int tid = threadIdx.x;
  const int w = tid >> 6, l = tid & 63, q = l >> 4, m = l & 15;
  const int r0w = rt * 256 + w * 64;
  const int cbase0 = cc * CHUNK;

  Lab[tid] = labels[cbase0 + tid];
  Lab[tid + 256] = labels[cbase0 + 256 + tid];

  // A-hi fragments only (64 VGPRs) -- round-4's extra Al[4][4] caused spill
  bf16x8 Ah[4][4];
  int labi[4][4];
#pragma unroll
  for (int tr = 0; tr < 4; ++tr) {
    const int row = r0w + tr * 16 + m;
#pragma unroll
    for (int ks = 0; ks < 4; ++ks)
      Ah[tr][ks] = *(const bf16x8*)&fhi[row * D + ks * 32 + q * 8];
#pragma unroll
    for (int v = 0; v < 4; ++v) labi[tr][v] = labels[r0w + tr * 16 + q * 4 + v];
  }

  float ps[4][4], as_[4][4], bgc = 0.f;
#pragma unroll
  for (int tr = 0; tr < 4; ++tr)
#pragma unroll
    for (int v = 0; v < 4; ++v) { ps[tr][v] = 0.f; as_[tr][v] = 0.f; }

  for (int it = 0; it < TILE_IT; ++it) {
    const int cbase = cbase0 + it * 128;
    __syncthreads();  // prior tile's LDS reads done (covers Lab for it=0)
#pragma unroll
    for (int n = 0; n < 8; ++n) {  // stage Bh+Bl via 16B global->LDS DMA
      const int r = w * 32 + n * 4 + q;
      const int c = m ^ (r & 15);  // XOR swizzle folded into global addr
      __builtin_amdgcn_global_load_lds(
          (const __attribute__((address_space(1))) unsigned*)
              &fhi[(size_t)(cbase + r) * D + c * 8],
          (__attribute__((address_space(3))) unsigned*)
              &Bh[(w * 512 + n * 64) * 8],
          16, 0, 0);
      __builtin_amdgcn_global_load_lds(
          (const __attribute__((address_space(1))) unsigned*)
              &flo[(size_t)(cbase + r) * D + c * 8],
          (__attribute__((address_space(3))) unsigned*)
              &Bl[(w * 512 + n * 64) * 8],
          16, 0, 0);
    }
    __syncthreads();  // drains vmcnt

    for (int ct = 0; ct < 8; ++ct) {
      const int jj = ct * 16 + m;
      const int jbase = cbase + ct * 16;
      const int labj = Lab[it * 128 + jj];
      f32x4 acc[4];
#pragma unroll
      for (int tr = 0; tr < 4; ++tr) acc[tr] = (f32x4){0.f, 0.f, 0.f, 0.f};
#pragma unroll
      for (int ks = 0; ks < 4; ++ks) {
        const int off = jj * 128 + ((ks * 4 + q) ^ m) * 8;  // swizzled chunk
        const bf16x8 bh = *(const bf16x8*)&Bh[off];
        const bf16x8 bl = *(const bf16x8*)&Bl[off];
#pragma unroll
        for (int tr = 0; tr < 4; ++tr)
          acc[tr] = __builtin_amdgcn_mfma_f32_16x16x32_bf16(Ah[tr][ks], bh, acc[tr], 0, 0, 0);
#pragma unroll
        for (int tr = 0; tr < 4; ++tr)
          acc[tr] = __builtin_amdgcn_mfma_f32_16x16x32_bf16(Ah[tr][ks], bl, acc[tr], 0, 0, 0);
      }
      bgc += (labj < 0) ? 1.0f : 0.0f;  // per-lane bg-column count (exact)
#pragma unroll
      for (int tr = 0; tr < 4; ++tr) {
        if (jbase == r0w + tr * 16) {  // wave-uniform: diagonal tile
#pragma unroll
          for (int v = 0; v < 4; ++v) {
            const float e = fast_exp2(acc[tr][v]);
            if (m == q * 4 + v) eself[jbase + m] = e;  // exact self term
            as_[tr][v] += e;
            ps[tr][v] += (labj == labi[tr][v]) ? e : 0.f;
          }
        } else {
#pragma unroll
          for (int v = 0; v < 4; ++v) {  // 5-op epilogue: exp,add,cmp,sel,add
            const float e = fast_exp2(acc[tr][v]);
            as_[tr][v] += e;
            ps[tr][v] += (labj == labi[tr][v]) ? e : 0.f;
          }
        }
      }
    }
  }

  // reduce over the 16 m-lanes (disjoint columns of each row)
  float vbg = bgc;
#pragma unroll
  for (int s = 1; s < 16; s <<= 1) vbg += __shfl_xor(vbg, s);
#pragma unroll
  for (int tr = 0; tr < 4; ++tr)
#pragma unroll
    for (int v = 0; v < 4; ++v) {
      float vp = ps[tr][v], va = as_[tr][v];
#pragma unroll
      for (int s = 1; s < 16; s <<= 1) {
        vp += __shfl_xor(vp, s);
        va += __shfl_xor(va, s);
      }
      if (m == 0)  // bg columns each contributed exactly e=1: subtract
        partials[(size_t)cc * N + r0w + tr * 16 + q * 4 + v] =
            make_float2(vp, va - vbg);
    }
}

// ---- kernel 3: combine chunks, exact corrections, loss, mean (finalizes) ---
__global__ __launch_bounds__(256) void cpe_rows(const float2* __restrict__ partials,
                                                const int* __restrict__ labels,
                                                const float* __restrict__ eself,
                                                float* __restrict__ accum,
                                                float* __restrict__ out) {
  const int r = blockIdx.x * 256 + threadIdx.x;
  float ps = 0.f, as_ = 0.f;
#pragma unroll
  for (int c = 0; c < NCHUNK; ++c) {
    const float2 p = partials[(size_t)c * N + r];
    ps += p.x;
    as_ += p.y;
  }
  const float es = eself[r];
  const int lab = labels[r];
  ps -= es;   // self always label-matches; exact cancellation if no positives
  as_ -= es;  // bg columns already removed per-chunk
  const bool valid = (lab >= 0) && (ps > 0.f);
  // |sim|<=10 => max-clamp inactive; all_sum*e^-M in [1,8191] => its clips
  // inactive; pos-clip binding forces loss=10 either way => clip-free form.
  float loss = 10.0f;
  if (ps > 0.f && as_ > 0.f) loss = fminf(logf(as_ / ps), 10.0f);
  float v0 = valid ? loss : 0.f;
  float v1 = valid ? 1.f : 0.f;
  float v2 = (lab >= 0) ? 1.f : 0.f;
#pragma unroll
  for (int s = 1; s < 64; s <<= 1) {
    v0 += __shfl_xor(v0, s);
    v1 += __shfl_xor(v1, s);
    v2 += __shfl_xor(v2, s);
  }
  __shared__ float red[3][4];
  const int w = threadIdx.x >> 6, l = threadIdx.x & 63;
  if (l == 0) { red[0][w] = v0; red[1][w] = v1; red[2][w] = v2; }
  __syncthreads();
  if (threadIdx.x == 0) {
    atomicAdd(&accum[0], red[0][0] + red[0][1] + red[0][2] + red[0][3]);
    atomicAdd(&accum[1], red[1][0] + red[1][1] + red[1][2] + red[1][3]);
    atomicAdd(&accum[2], red[2][0] + red[2][1] + red[2][2] + red[2][3]);
    __threadfence();
    const unsigned old = atomicAdd((unsigned*)&accum[3], 1u);
    if (old == gridDim.x - 1) {  // last block finalizes
      const float ls = atomicAdd(&accum[0], 0.0f);
      const float nv = atomicAdd(&accum[1], 0.0f);
      const float nf = atomicAdd(&accum[2], 0.0f);
      out[0] = (nf >= 2.0f && nv > 0.f) ? ls / fmaxf(nv, 1.f) : 0.0f;
    }
  }
}

extern "C" void kernel_launch(void* const* d_in, const int* in_sizes, int n_in,
                              void* d_out, int out_size, void* d_ws, size_t ws_size,
                              hipStream_t stream) {
  const float* feat = (const float*)d_in[0];
  const int* labels = (const int*)d_in[1];
  float* out = (float*)d_out;
  char* ws = (char*)d_ws;
  u16* fhi = (u16*)ws;                          // 2 MB
  u16* flo = (u16*)(ws + 2097152);              // 2 MB
  float2* partials = (float2*)(ws + 4194304);   // 16*8192*8 = 1 MB
  float* eself = (float*)(ws + 5242880);        // 32 KB
  float* accum = (float*)(ws + 5275648);        // loss-sum, n_valid, n_fg, ctr

  cpe_prep<<<N / 16, 256, 0, stream>>>(feat, labels, fhi, flo, accum);
  cpe_main<<<dim3(N / 256, NCHUNK), 256, 0, stream>>>(fhi, flo, labels, partials, eself);
  cpe_rows<<<N / 256, 256, 0, stream>>>(partials, labels, eself, accum, out);
}

// Round 6
// 139.777 us; speedup vs baseline: 1.7587x; 1.0730x over previous
//
#include <hip/hip_runtime.h>

#define N 8192
#define D 128
#define CHUNK 512
#define NCHUNK 16
#define TILE_IT 4
// sqrt(10): dot of two scaled rows = cos_sim/T directly; e = __expf(acc)
#define PREP_SCALE 3.16227766017f

typedef unsigned short u16;
typedef __attribute__((ext_vector_type(8))) __bf16 bf16x8;
typedef __attribute__((ext_vector_type(4))) float f32x4;

__device__ __forceinline__ u16 f2bf(float x) {
  unsigned u = __float_as_uint(x);
  u += 0x7fff + ((u >> 16) & 1);  // RNE
  return (u16)(u >> 16);
}
__device__ __forceinline__ float bf2f(u16 h) {
  return __uint_as_float(((unsigned)h) << 16);
}

// ---- kernel 1: normalize+scale rows, ZERO bg rows, split hi/lo; zero accum -
__global__ __launch_bounds__(256) void cpe_prep(const float* __restrict__ feat,
                                                const int* __restrict__ labels,
                                                u16* __restrict__ fhi,
                                                u16* __restrict__ flo,
                                                float* __restrict__ accum,
                                                int* __restrict__ cnt) {
  if (blockIdx.x == 0) {
    if (threadIdx.x < 4) accum[threadIdx.x] = 0.0f;
    if (threadIdx.x < 32) cnt[threadIdx.x] = 0;
  }
  const int w = threadIdx.x >> 6, l = threadIdx.x & 63, q = l >> 4, m = l & 15;
  const int row = (int)blockIdx.x * 16 + w * 4 + q;  // 16 rows/block
  const int lab = labels[row];
  const float4 x0 = *(const float4*)&feat[row * D + m * 8];
  const float4 x1 = *(const float4*)&feat[row * D + m * 8 + 4];
  float s = x0.x * x0.x + x0.y * x0.y + x0.z * x0.z + x0.w * x0.w +
            x1.x * x1.x + x1.y * x1.y + x1.z * x1.z + x1.w * x1.w;
#pragma unroll
  for (int sh = 1; sh < 16; sh <<= 1) s += __shfl_xor(s, sh);
  float inv = PREP_SCALE / fmaxf(sqrtf(s), 1e-12f);
  if (lab < 0) inv = 0.0f;  // bg rows -> sim=0 -> e=1, subtracted exactly later
  const float a[8] = {x0.x * inv, x0.y * inv, x0.z * inv, x0.w * inv,
                      x1.x * inv, x1.y * inv, x1.z * inv, x1.w * inv};
  u16 h[8], lo[8];
#pragma unroll
  for (int k = 0; k < 8; ++k) {
    h[k] = f2bf(a[k]);
    lo[k] = f2bf(a[k] - bf2f(h[k]));
  }
  *(ushort4*)&fhi[row * D + m * 8] = make_ushort4(h[0], h[1], h[2], h[3]);
  *(ushort4*)&fhi[row * D + m * 8 + 4] = make_ushort4(h[4], h[5], h[6], h[7]);
  *(ushort4*)&flo[row * D + m * 8] = make_ushort4(lo[0], lo[1], lo[2], lo[3]);
  *(ushort4*)&flo[row * D + m * 8 + 4] = make_ushort4(lo[4], lo[5], lo[6], lo[7]);
}

// ---- kernel 2: sim = Ah·(Bh+Bl); Ah in regs, Bh+Bl in LDS; fused row-fold --
// Grid (32, 16): block = 256 rows x 512-col chunk; wave owns 64 rows.
__global__ __launch_bounds__(256, 2) void cpe_main(
    const u16* __restrict__ fhi, const u16* __restrict__ flo,
    const int* __restrict__ labels, float2* __restrict__ partials,
    float* __restrict__ eself, float* __restrict__ accum,
    int* __restrict__ cnt, float* __restrict__ out) {
  __shared__ __align__(16) u16 Bh[128 * 128];  // 32 KB, XOR-swizzled chunks
  __shared__ __align__(16) u16 Bl[128 * 128];  // 32 KB
  __shared__ int Lab[CHUNK];                   // 2 KB
  __shared__ float red[2][4];
  __shared__ int lastflag;
  const int rt = blockIdx.x, cc = blockIdx.y;
  const int tid = threadIdx.x;
  const int w = tid >> 6, l = tid & 63, q = l >> 4, m = l & 15;
  const int r0w = rt * 256 + w * 64;
  const int cbase0 = cc * CHUNK;

  Lab[tid] = labels[cbase0 + tid];
  Lab[tid + 256] = labels[cbase0 + 256 + tid];

  // A-hi fragments only (64 VGPRs); lo term handled on the B side in LDS
  bf16x8 Ah[4][4];
  int labi[4][4];
#pragma unroll
  for (int tr = 0; tr < 4; ++tr) {
    const int row = r0w + tr * 16 + m;
#pragma unroll
    for (int ks = 0; ks < 4; ++ks)
      Ah[tr][ks] = *(const bf16x8*)&fhi[row * D + ks * 32 + q * 8];
#pragma unroll
    for (int v = 0; v < 4; ++v) labi[tr][v] = labels[r0w + tr * 16 + q * 4 + v];
  }

  // staging lane-offsets (u16 elements), fixed across tiles: hoisted
  int goff[8];
#pragma unroll
  for (int n = 0; n < 8; ++n) {
    const int r = w * 32 + n * 4 + q;
    goff[n] = r * D + (m ^ (r & 15)) * 8;  // XOR swizzle folded in global addr
  }

  float ps[4][4], as_[4][4], es_reg[4], bgc = 0.f;
#pragma unroll
  for (int tr = 0; tr < 4; ++tr) {
    es_reg[tr] = 0.f;
#pragma unroll
    for (int v = 0; v < 4; ++v) { ps[tr][v] = 0.f; as_[tr][v] = 0.f; }
  }

  for (int it = 0; it < TILE_IT; ++it) {
    const int cbase = cbase0 + it * 128;
    const u16* th = fhi + (size_t)cbase * D;
    const u16* tl = flo + (size_t)cbase * D;
    __syncthreads();  // prior tile's LDS reads done (covers Lab for it=0)
#pragma unroll
    for (int n = 0; n < 8; ++n) {  // stage Bh+Bl via 16B global->LDS DMA
      __builtin_amdgcn_global_load_lds(
          (const __attribute__((address_space(1))) unsigned*)&th[goff[n]],
          (__attribute__((address_space(3))) unsigned*)&Bh[(w * 512 + n * 64) * 8],
          16, 0, 0);
      __builtin_amdgcn_global_load_lds(
          (const __attribute__((address_space(1))) unsigned*)&tl[goff[n]],
          (__attribute__((address_space(3))) unsigned*)&Bl[(w * 512 + n * 64) * 8],
          16, 0, 0);
    }
    __syncthreads();  // drains vmcnt

    for (int ct = 0; ct < 8; ++ct) {
      const int jj = ct * 16 + m;
      const int jbase = cbase + ct * 16;
      const int labj = Lab[it * 128 + jj];
      f32x4 acc[4];
#pragma unroll
      for (int tr = 0; tr < 4; ++tr) acc[tr] = (f32x4){0.f, 0.f, 0.f, 0.f};
#pragma unroll
      for (int ks = 0; ks < 4; ++ks) {
        const int off = jj * 128 + ((ks * 4 + q) ^ m) * 8;  // swizzled chunk
        const bf16x8 bh = *(const bf16x8*)&Bh[off];
        const bf16x8 bl = *(const bf16x8*)&Bl[off];
#pragma unroll
        for (int tr = 0; tr < 4; ++tr)
          acc[tr] = __builtin_amdgcn_mfma_f32_16x16x32_bf16(Ah[tr][ks], bh, acc[tr], 0, 0, 0);
#pragma unroll
        for (int tr = 0; tr < 4; ++tr)
          acc[tr] = __builtin_amdgcn_mfma_f32_16x16x32_bf16(Ah[tr][ks], bl, acc[tr], 0, 0, 0);
      }
      bgc += (labj < 0) ? 1.0f : 0.0f;  // per-lane bg-column count (exact)
#pragma unroll
      for (int tr = 0; tr < 4; ++tr) {
        float e4[4];
#pragma unroll
        for (int v = 0; v < 4; ++v) {  // uniform 5-op epilogue, emitted ONCE
          const float e = __expf(acc[tr][v]);
          e4[v] = e;
          as_[tr][v] += e;
          ps[tr][v] += (labj == labi[tr][v]) ? e : 0.f;
        }
        if (jbase == r0w + tr * 16) {  // wave-uniform: register capture only
#pragma unroll
          for (int v = 0; v < 4; ++v)
            if (m == q * 4 + v) es_reg[tr] = e4[v];
        }
      }
    }
  }

  // exact self terms to global, once (lane q==m>>2 holds row r0w+tr*16+m)
  if (cc == (rt >> 1) && q == (m >> 2)) {
#pragma unroll
    for (int tr = 0; tr < 4; ++tr) eself[r0w + tr * 16 + m] = es_reg[tr];
  }

  // reduce over the 16 m-lanes (disjoint columns of each row)
  float vbg = bgc;
#pragma unroll
  for (int s = 1; s < 16; s <<= 1) vbg += __shfl_xor(vbg, s);
#pragma unroll
  for (int tr = 0; tr < 4; ++tr)
#pragma unroll
    for (int v = 0; v < 4; ++v) {
      float vp = ps[tr][v], va = as_[tr][v];
#pragma unroll
      for (int s = 1; s < 16; s <<= 1) {
        vp += __shfl_xor(vp, s);
        va += __shfl_xor(va, s);
      }
      if (m == 0)  // bg columns each contributed exactly e=1: subtract
        partials[(size_t)cc * N + r0w + tr * 16 + q * 4 + v] =
            make_float2(vp, va - vbg);
    }

  // ---- fused fold: last block of this row group reduces 256 rows ----------
  __threadfence();  // release this thread's partials/eself stores
  __syncthreads();
  if (tid == 0) lastflag = (atomicAdd(&cnt[rt], 1) == NCHUNK - 1) ? 1 : 0;
  __syncthreads();
  if (lastflag) {
    __threadfence();  // acquire: see all 16 blocks' stores
    const int r = rt * 256 + tid;
    float fps = 0.f, fas = 0.f;
#pragma unroll
    for (int c = 0; c < NCHUNK; ++c) {
      const float2 p = partials[(size_t)c * N + r];
      fps += p.x;
      fas += p.y;
    }
    const float es = eself[r];
    const int lab = labels[r];
    fps -= es;  // self always label-matches; exact cancel if no positives
    fas -= es;  // bg columns already removed per-chunk
    const bool valid = (lab >= 0) && (fps > 0.f);
    // |sim|<=10 => max-clamp inactive; all_sum*e^-M in [1,8191] => its clips
    // inactive; pos-clip binding forces loss=10 either way => clip-free form.
    float loss = 10.0f;
    if (fps > 0.f && fas > 0.f) loss = fminf(logf(fas / fps), 10.0f);
    float v0 = valid ? loss : 0.f;
    float v1 = valid ? 1.f : 0.f;
#pragma unroll
    for (int s = 1; s < 64; s <<= 1) {
      v0 += __shfl_xor(v0, s);
      v1 += __shfl_xor(v1, s);
    }
    if (l == 0) { red[0][w] = v0; red[1][w] = v1; }
    __syncthreads();
    if (tid == 0) {
      atomicAdd(&accum[0], red[0][0] + red[0][1] + red[0][2] + red[0][3]);
      atomicAdd(&accum[1], red[1][0] + red[1][1] + red[1][2] + red[1][3]);
      __threadfence();
      const unsigned old = atomicAdd((unsigned*)&accum[3], 1u);
      if (old == 31u) {  // last row-group reducer finalizes
        const float ls = atomicAdd(&accum[0], 0.0f);
        const float nv = atomicAdd(&accum[1], 0.0f);
        out[0] = (nv > 0.f) ? ls / nv : 0.0f;  // nv>0 implies nfg>=2
      }
    }
  }
}

extern "C" void kernel_launch(void* const* d_in, const int* in_sizes, int n_in,
                              void* d_out, int out_size, void* d_ws, size_t ws_size,
                              hipStream_t stream) {
  const float* feat = (const float*)d_in[0];
  const int* labels = (const int*)d_in[1];
  float* out = (float*)d_out;
  char* ws = (char*)d_ws;
  u16* fhi = (u16*)ws;                          // 2 MB
  u16* flo = (u16*)(ws + 2097152);              // 2 MB
  float2* partials = (float2*)(ws + 4194304);   // 16*8192*8 = 1 MB
  float* eself = (float*)(ws + 5242880);        // 32 KB
  float* accum = (float*)(ws + 5275648);        // loss-sum, n_valid, -, ctr
  int* cnt = (int*)(ws + 5275904);              // 32 per-row-group counters

  cpe_prep<<<N / 16, 256, 0, stream>>>(feat, labels, fhi, flo, accum, cnt);
  cpe_main<<<dim3(N / 256, NCHUNK), 256, 0, stream>>>(fhi, flo, labels, partials,
                                                      eself, accum, cnt, out);
}